// Round 6
// baseline (201.981 us; speedup 1.0000x reference)
//
#include <hip/hip_runtime.h>

// Problem constants (from reference): B,R,C,H,W = 4,2,19,256,512
constexpr int B = 4, R = 2, C = 19, H = 256, W = 512;
constexpr int HW = H * W;

// R6: NO LDS, NO BARRIERS. R1/R4/R5 proved the LDS-staged variants are all
// pinned at 51-53 us regardless of banking or drain placement — the barrier'd
// staging phase structure was the floor. Direct cached gathers instead:
//   - per (block,channel) gather footprint = ~26 KB (2 refs) -> L1-class
//   - per (XCD,channel) footprint ~0.6 MB -> L2 (4 MB), pinned by XCD swizzle
//   - tap math identical to the proven fallback path (exact for any |mv|)
// No sync structure at all -> waves pipeline channels independently; no LDS
// -> occupancy is VGPR-bound (~7 blocks/CU at 72 VGPR vs 3 before).
//
// PIXEL->THREAD MAP (R5, kept): wave w (= t>>6) owns rows y0+4w+p (p=0..3);
// lane (= t&63) is the x offset -> every gather instruction reads 64
// consecutive-ish floats (span ~5 cachelines incl. jitter): TA-coalesced.
// mv/wgt loads and out stores are exact 256B wave ops.
constexpr int BX = 64, BY = 16;
constexpr int NBX = W / BX;              // 8
constexpr int NBY = H / BY;              // 16
constexpr int NSPAT = B * NBX * NBY;     // 512 spatial tiles
constexpr int NCHUNK = 4;                // 2048 blocks; mv/wgt re-read x4 is ~cheap

// Register regime: launch_bounds(256,4) proven no-spill (VGPR ~72 -> natural
// occupancy 512/72 = 7 waves/SIMD; the 2nd arg is only a floor, not a cap).
// DO NOT tighten (R2: cap -> VGPR 40 -> tap state spilled, 3x slower).
__global__ __launch_bounds__(256, 4) void mc_warp_kernel(
    const float* __restrict__ pred,   // [B,R,C,H,W]
    const float* __restrict__ mv,     // [B,R,2,H,W] quarter-pel
    const float* __restrict__ wgt,    // [B,R,1,H,W]
    float* __restrict__ out)          // [B,C,H,W]
{
    int t = threadIdx.x;
    // XCD band swizzle on the spatial index: each XCD owns a contiguous
    // (b, y-band); all channel-chunks of a tile land on the same XCD
    // (gridDim.x = 512 is a multiple of 8) -> pred/mv/wgt L2 locality.
    int xcd  = blockIdx.x & 7;
    int slot = blockIdx.x >> 3;
    int vblk = xcd * (NSPAT / 8) + slot;
    int bx   = vblk & (NBX - 1);
    int by   = (vblk >> 3) & (NBY - 1);
    int b    = vblk >> 7;
    int x0 = bx * BX, y0 = by * BY;
    int lane = t & 63, wv = t >> 6;
    int x  = x0 + lane;                  // this thread's x (all 4 px share it)
    int yb = y0 + wv * 4;                // px p of this thread = row yb + p

    const float* pl0 = pred + (size_t)(b * R + 0) * C * HW;
    const float* pl1 = pred + (size_t)(b * R + 1) * C * HW;

    int cbeg = (C * blockIdx.y) / NCHUNK;        // {0,4,9,14}
    int cend = (C * (blockIdx.y + 1)) / NCHUNK;  // {4,9,14,19}

    // Per-(ref, px) tap state: two row-base offsets + 4 routed weights.
    // Same (proven) border math as every passing round: x-pair shifted into
    // [0, W-2] with wA/wB routing; y taps clamped with weights zeroed outside.
    int   off0[R][4], off1[R][4];
    float wq[R][4][4];

    #pragma unroll
    for (int r = 0; r < R; ++r) {
        const float* mvx = mv + (size_t)((b * R + r) * 2) * HW;
        const float* mvy = mvx + HW;
        const float* wp  = wgt + (size_t)(b * R + r) * HW;
        #pragma unroll
        for (int p = 0; p < 4; ++p) {
            int yy = yb + p;
            size_t ro = (size_t)yy * W + x;       // 256B-coalesced per wave
            float mx = mvx[ro], my = mvy[ro], wr = wp[ro];

            float gx = (float)x  + mx * 0.25f;    // quarter-pel -> pixel
            float gy = (float)yy + my * 0.25f;
            float fx0 = floorf(gx), fy0 = floorf(gy);
            float wx1 = gx - fx0, wx0 = 1.0f - wx1;
            float wy1 = gy - fy0, wy0 = 1.0f - wy1;
            int ix0 = (int)fx0, iy0 = (int)fy0;
            int ix1 = ix0 + 1,  iy1 = iy0 + 1;

            int base = min(max(ix0, 0), W - 2);
            float wA = (ix0 == base)     ? wx0 : ((ix1 == base)     ? wx1 : 0.0f);
            float wB = (ix1 == base + 1) ? wx1 : ((ix0 == base + 1) ? wx0 : 0.0f);
            float wy0v = ((iy0 >= 0) && (iy0 < H)) ? wy0 * wr : 0.0f;
            float wy1v = ((iy1 >= 0) && (iy1 < H)) ? wy1 * wr : 0.0f;
            int cy0 = min(max(iy0, 0), H - 1);
            int cy1 = min(max(iy1, 0), H - 1);

            off0[r][p] = cy0 * W + base;
            off1[r][p] = cy1 * W + base;
            wq[r][p][0] = wy0v * wA;
            wq[r][p][1] = wy0v * wB;
            wq[r][p][2] = wy1v * wA;
            wq[r][p][3] = wy1v * wB;
        }
    }

    float* ob = out + (size_t)b * C * HW + (size_t)yb * W + x;

    // Channel loop: 32 independent cached loads per iteration (addresses
    // precomputed, no cross-iteration deps, no barriers) -> the scheduler
    // overlaps loads/FMA freely and ~28 resident waves/CU hide L1/L2 latency.
    for (int c = cbeg; c < cend; ++c) {
        const float* pc0 = pl0 + (size_t)c * HW;
        const float* pc1 = pl1 + (size_t)c * HW;
        float res[4];
        #pragma unroll
        for (int p = 0; p < 4; ++p) {
            float a00 = pc0[off0[0][p]], a01 = pc0[off0[0][p] + 1];
            float a10 = pc0[off1[0][p]], a11 = pc0[off1[0][p] + 1];
            float b00 = pc1[off0[1][p]], b01 = pc1[off0[1][p] + 1];
            float b10 = pc1[off1[1][p]], b11 = pc1[off1[1][p] + 1];
            res[p] = wq[0][p][0] * a00 + wq[0][p][1] * a01
                   + wq[0][p][2] * a10 + wq[0][p][3] * a11
                   + wq[1][p][0] * b00 + wq[1][p][1] * b01
                   + wq[1][p][2] * b10 + wq[1][p][3] * b11;
        }
        // 4 row stores, each a 256B-coalesced wave store.
        float* oc = ob + (size_t)c * HW;
        #pragma unroll
        for (int p = 0; p < 4; ++p)
            oc[(size_t)p * W] = res[p];
    }
}

extern "C" void kernel_launch(void* const* d_in, const int* in_sizes, int n_in,
                              void* d_out, int out_size, void* d_ws, size_t ws_size,
                              hipStream_t stream) {
    const float* pred = (const float*)d_in[0];   // [B,R,C,H,W] fp32
    const float* mv   = (const float*)d_in[1];   // [B,R,2,H,W] fp32
    const float* wgt  = (const float*)d_in[2];   // [B,R,1,H,W] fp32
    float* out = (float*)d_out;                  // [B,C,H,W] fp32

    dim3 grid(NSPAT, NCHUNK);            // 512 spatial tiles x 4 channel chunks
    mc_warp_kernel<<<grid, dim3(256), 0, stream>>>(pred, mv, wgt, out);
}

// Round 7
// 148.242 us; speedup vs baseline: 1.3625x; 1.3625x over previous
//
#include <hip/hip_runtime.h>

// Problem constants (from reference): B,R,C,H,W = 4,2,19,256,512
constexpr int B = 4, R = 2, C = 19, H = 256, W = 512;
constexpr int HW = H * W;

// Output tile per block: 64 x 16 px; 256 threads = 4 waves.
// PIXEL->THREAD MAP (R5, proven): wave w (= t>>6) owns rows y0+4w+p (p=0..3);
// lane (= t&63) is the x offset. Gathers read ~64 consecutive floats/wave;
// mv/wgt loads and out stores are exact 256B wave ops.
//
// HISTORY (dispatch us): R1 single-buf 31KB = 51.4 | R4 dbuf 52.7KB = 52.5 |
// R5 +remap = 53 | R6 no-LDS global gather = 101.6 (2x WORSE; gather VMEM
// cost >> LDS; conflicts=0 proved conflicts are staging-DMA-inherent).
// All LDS variants pinned ~52 with nothing saturated (VALU 23%, HBM 25%,
// Occ 25-33%) -> concurrency-starved at 2-3 blocks/CU. R7: single buffer +
// lean tile -> 26 KB/block -> 5-6 blocks/CU.
constexpr int BX = 64, BY = 16;
constexpr int NBX = W / BX;              // 8
constexpr int NBY = H / BY;              // 16
constexpr int NSPAT = B * NBX * NBY;     // 512 spatial tiles
constexpr int NCHUNK = 4;                // 2048 blocks = 8/CU available

// Pred tile staged in LDS per (channel, ref), SINGLE-buffered.
// Halo: x in [-12,+11] (colbase = x0-12, float4-aligned), y in [-10,+10].
// Escape prob ~1e-6/px-ref -> ~0.25% of blocks take the (correct) global
// fallback. 2 tiles x 13.02 KB = 26.05 KB/block -> 5-6 blocks/CU.
constexpr int TW = 88;                   // 22 float4s per row
constexpr int TH = 37;                   // 16 + 10 up + 11 down
constexpr int TILE_N = TW * TH;          // 3256 floats = 13.02 KB
constexpr int TILE_V4 = TILE_N / 4;      // 814 float4s
// TW = 22*4 exactly -> tile rows pack contiguously: phys float index of the
// idx-th float4 is idx*4, i.e. exactly the wave-linear layout global_load_lds
// needs (uniform LDS base + lane*16B, per-lane GLOBAL source address).

// Direct global->LDS DMA, 16B per lane. No VGPR round-trip (register staging
// buffers spill to scratch: proven 2.4-3x slower, twice).
#define GLD_LDS16(gsrc, ldst)                                                  \
    __builtin_amdgcn_global_load_lds(                                          \
        (const __attribute__((address_space(1))) void*)(gsrc),                 \
        (__attribute__((address_space(3))) void*)(ldst), 16, 0, 0)

// Register regime: launch_bounds(256,4), VGPR ~72, zero spill. 72 VGPR allows
// 7 waves/SIMD -> not binding at the 6-block LDS cap. DO NOT tighten the
// bound (R2: cap -> VGPR 40 -> tap-state spill -> 3x slower).
//
// SYNC RULE (R3 failure, absmax 6.06): __syncthreads_or does NOT carry the
// vmcnt(0) drain that __syncthreads does. Every global_load_lds -> ds_read
// handoff MUST cross a plain __syncthreads().
__global__ __launch_bounds__(256, 4) void mc_warp_kernel(
    const float* __restrict__ pred,   // [B,R,C,H,W]
    const float* __restrict__ mv,     // [B,R,2,H,W] quarter-pel
    const float* __restrict__ wgt,    // [B,R,1,H,W]
    float* __restrict__ out)          // [B,C,H,W]
{
    __shared__ float tiles[2][TILE_N];   // [ref][tile], single-buffered

    int t = threadIdx.x;
    // XCD band swizzle on the spatial index: each XCD owns a contiguous
    // (b, y-band); all channel-chunks of a tile land on the same XCD
    // (gridDim.x = 512 is a multiple of 8) -> pred/mv/wgt L2 locality.
    int xcd  = blockIdx.x & 7;
    int slot = blockIdx.x >> 3;
    int vblk = xcd * (NSPAT / 8) + slot;
    int bx   = vblk & (NBX - 1);
    int by   = (vblk >> 3) & (NBY - 1);
    int b    = vblk >> 7;
    int x0 = bx * BX, y0 = by * BY;
    int lane = t & 63, wv = t >> 6;
    int x  = x0 + lane;                  // this thread's x (all 4 px share it)
    int yb = y0 + wv * 4;                // px p of this thread = row yb + p

    // Tile origin, clamped fully inside the image (staging needs no clamps).
    // colbase stays float4-aligned (x0 mult of 64, W-TW = 424 mult of 4).
    int rowbase = min(max(y0 - 10, 0), H - TH);
    int colbase = min(max(x0 - 12, 0), W - TW);

    const float* pl0 = pred + (size_t)(b * R + 0) * C * HW;
    const float* pl1 = pred + (size_t)(b * R + 1) * C * HW;
    const float* st0 = pl0 + (size_t)rowbase * W + colbase;
    const float* st1 = pl1 + (size_t)rowbase * W + colbase;

    int cbeg = (C * blockIdx.y) / NCHUNK;        // {0,4,9,14}
    int cend = (C * (blockIdx.y + 1)) / NCHUNK;  // {4,9,14,19}

    // Issue the FIRST channel's staging now; it overlaps the ~300-op tap
    // setup below and is drained by the first loop-body __syncthreads().
    {
        const float* s0 = st0 + (size_t)cbeg * HW;
        const float* s1 = st1 + (size_t)cbeg * HW;
        #pragma unroll
        for (int i = 0; i < 4; ++i) {
            int idx = t + i * 256;
            if (idx < TILE_V4) {
                int row = idx / 22;               // 22 float4s per tile row
                int off = idx * 4 + row * (W - TW);   // == row*W + c4
                GLD_LDS16(s0 + off, &tiles[0][idx * 4]);
                GLD_LDS16(s1 + off, &tiles[1][idx * 4]);
            }
        }
    }

    // Per-(ref, px) tap state: two row-pair offsets + 4 pair weights.
    int   off0[R][4], off1[R][4];
    int   offL0[R][4], offL1[R][4], offG0[R][4], offG1[R][4];
    float wq[R][4][4];
    int flag = 0;

    #pragma unroll
    for (int r = 0; r < R; ++r) {
        const float* mvx = mv + (size_t)((b * R + r) * 2) * HW;
        const float* mvy = mvx + HW;
        const float* wp  = wgt + (size_t)(b * R + r) * HW;
        #pragma unroll
        for (int p = 0; p < 4; ++p) {
            int yy = yb + p;
            size_t ro = (size_t)yy * W + x;       // 256B-coalesced per wave
            float mx = mvx[ro], my = mvy[ro], wr = wp[ro];

            float gx = (float)x  + mx * 0.25f;    // quarter-pel -> pixel
            float gy = (float)yy + my * 0.25f;
            float fx0 = floorf(gx), fy0 = floorf(gy);
            float wx1 = gx - fx0, wx0 = 1.0f - wx1;
            float wy1 = gy - fy0, wy0 = 1.0f - wy1;
            int ix0 = (int)fx0, iy0 = (int)fy0;
            int ix1 = ix0 + 1,  iy1 = iy0 + 1;

            // x pair: shift base into [0, W-2], route wx0/wx1 per element.
            int base = min(max(ix0, 0), W - 2);
            float wA = (ix0 == base)     ? wx0 : ((ix1 == base)     ? wx1 : 0.0f);
            float wB = (ix1 == base + 1) ? wx1 : ((ix0 == base + 1) ? wx0 : 0.0f);
            float wy0v = ((iy0 >= 0) && (iy0 < H)) ? wy0 * wr : 0.0f;
            float wy1v = ((iy1 >= 0) && (iy1 < H)) ? wy1 * wr : 0.0f;
            int cy0 = min(max(iy0, 0), H - 1);
            int cy1 = min(max(iy1, 0), H - 1);

            int l0 = base - colbase;
            int r0 = cy0 - rowbase, r1 = cy1 - rowbase;
            bool anyx = (wA != 0.0f) || (wB != 0.0f);
            bool anyy = (wy0v != 0.0f) || (wy1v != 0.0f);
            bool cb  = (l0 < 0 || l0 > TW - 2) && anyx && anyy;
            bool rb0 = (r0 < 0 || r0 > TH - 1) && (wy0v != 0.0f) && anyx;
            bool rb1 = (r1 < 0 || r1 > TH - 1) && (wy1v != 0.0f) && anyx;
            flag |= (int)(cb || rb0 || rb1);
            l0 = min(max(l0, 0), TW - 2);
            r0 = min(max(r0, 0), TH - 1);
            r1 = min(max(r1, 0), TH - 1);

            offL0[r][p] = r0 * TW + l0;
            offL1[r][p] = r1 * TW + l0;
            offG0[r][p] = cy0 * W + base;
            offG1[r][p] = cy1 * W + base;
            wq[r][p][0] = wy0v * wA;
            wq[r][p][1] = wy0v * wB;
            wq[r][p][2] = wy1v * wA;
            wq[r][p][3] = wy1v * wB;
        }
    }

    // Block-uniform fallback: if ANY tap escaped the halo, the whole block
    // uses global gathers instead of LDS. Flag reduction ONLY — memory
    // ordering comes from the plain __syncthreads() in the loop.
    int fbB = __syncthreads_or(flag);
    #pragma unroll
    for (int r = 0; r < R; ++r)
        #pragma unroll
        for (int p = 0; p < 4; ++p) {
            off0[r][p] = fbB ? offG0[r][p] : offL0[r][p];
            off1[r][p] = fbB ? offG1[r][p] : offL1[r][p];
        }

    float* ob = out + (size_t)b * C * HW + (size_t)yb * W + x;

    for (int c = cbeg; c < cend; ++c) {
        if (c > cbeg) {
            __syncthreads();             // compute(c-1)'s LDS readers done
            if (!fbB) {                  // stage(c) over the single buffer
                const float* s0 = st0 + (size_t)c * HW;
                const float* s1 = st1 + (size_t)c * HW;
                #pragma unroll
                for (int i = 0; i < 4; ++i) {
                    int idx = t + i * 256;
                    if (idx < TILE_V4) {
                        int row = idx / 22;
                        int off = idx * 4 + row * (W - TW);
                        GLD_LDS16(s0 + off, &tiles[0][idx * 4]);
                        GLD_LDS16(s1 + off, &tiles[1][idx * 4]);
                    }
                }
            }
        }
        __syncthreads();                 // drains stage(c) (vmcnt0 + barrier)

        float res[4];
        if (!fbB) {
            const float* tb0 = &tiles[0][0];
            const float* tb1 = &tiles[1][0];
            #pragma unroll
            for (int p = 0; p < 4; ++p) {
                float a00 = tb0[off0[0][p]], a01 = tb0[off0[0][p] + 1];
                float a10 = tb0[off1[0][p]], a11 = tb0[off1[0][p] + 1];
                float b00 = tb1[off0[1][p]], b01 = tb1[off0[1][p] + 1];
                float b10 = tb1[off1[1][p]], b11 = tb1[off1[1][p] + 1];
                res[p] = wq[0][p][0] * a00 + wq[0][p][1] * a01
                       + wq[0][p][2] * a10 + wq[0][p][3] * a11
                       + wq[1][p][0] * b00 + wq[1][p][1] * b01
                       + wq[1][p][2] * b10 + wq[1][p][3] * b11;
            }
        } else {
            const float* pc0 = pl0 + (size_t)c * HW;
            const float* pc1 = pl1 + (size_t)c * HW;
            #pragma unroll
            for (int p = 0; p < 4; ++p) {
                float a00 = pc0[off0[0][p]], a01 = pc0[off0[0][p] + 1];
                float a10 = pc0[off1[0][p]], a11 = pc0[off1[0][p] + 1];
                float b00 = pc1[off0[1][p]], b01 = pc1[off0[1][p] + 1];
                float b10 = pc1[off1[1][p]], b11 = pc1[off1[1][p] + 1];
                res[p] = wq[0][p][0] * a00 + wq[0][p][1] * a01
                       + wq[0][p][2] * a10 + wq[0][p][3] * a11
                       + wq[1][p][0] * b00 + wq[1][p][1] * b01
                       + wq[1][p][2] * b10 + wq[1][p][3] * b11;
            }
        }
        // 4 row stores, each a 256B-coalesced wave store.
        float* oc = ob + (size_t)c * HW;
        #pragma unroll
        for (int p = 0; p < 4; ++p)
            oc[(size_t)p * W] = res[p];
    }
}

extern "C" void kernel_launch(void* const* d_in, const int* in_sizes, int n_in,
                              void* d_out, int out_size, void* d_ws, size_t ws_size,
                              hipStream_t stream) {
    const float* pred = (const float*)d_in[0];   // [B,R,C,H,W] fp32
    const float* mv   = (const float*)d_in[1];   // [B,R,2,H,W] fp32
    const float* wgt  = (const float*)d_in[2];   // [B,R,1,H,W] fp32
    float* out = (float*)d_out;                  // [B,C,H,W] fp32

    dim3 grid(NSPAT, NCHUNK);            // 512 spatial tiles x 4 channel chunks
    mc_warp_kernel<<<grid, dim3(256), 0, stream>>>(pred, mv, wgt, out);
}